// Round 3
// baseline (120.964 us; speedup 1.0000x reference)
//
#include <hip/hip_runtime.h>
#include <math.h>
#include <stdint.h>

#define NEXP 48
#define NCAT 30
#define SP_TOT 13440            // 24*28*20
#define M_TOT (NCAT * SP_TOT)   // 403200
#define CPB 64                  // columns per block
#define PAD 52                  // words per column: 208B stride -> 16B aligned, read-bank-disjoint

// Cooperative top-K + contraction. 8 threads per column, 2 columns per thread.
// Fast path: strict |value| compares (v_cmp_gt_f32 with free abs modifiers).
// Exact-tie columns detected via sum-of-ranks != C(48,2) and redone with
// u64 keys (abs_bits<<32 | (47-e)) reproducing jax.lax.top_k stable order.
__global__ __launch_bounds__(256) void moe_topk_contract(
    const float* __restrict__ gm, const float* __restrict__ gf,
    const float* __restrict__ se, const int* __restrict__ kptr,
    float* __restrict__ out)
{
    __shared__ __align__(16) float gv[CPB * PAD];

    const int tid       = threadIdx.x;
    const int colbase   = blockIdx.x * CPB;
    const int col_local = tid >> 3;     // 0..31
    const int sub       = tid & 7;      // 0..7
    const int cA        = col_local;
    const int cB        = col_local + 32;
    const int colA      = colbase + cA;
    const int colB      = colbase + cB;
    const int K         = *kptr;

    #pragma unroll 1
    for (int t = 0; t < 2; ++t) {
        const float* __restrict__ g_ = t ? gf : gm;

        // ---- stage 48 experts x 64 cols as raw floats (coalesced, b64 LDS writes)
        #pragma unroll
        for (int rep = 0; rep < 6; ++rep) {
            const int e2 = rep * 8 + (tid >> 6) * 2;   // even, 0..46
            const int c  = tid & 63;
            const float v0 = g_[e2 * M_TOT + colbase + c];
            const float v1 = g_[(e2 + 1) * M_TOT + colbase + c];
            *(float2*)&gv[c * PAD + e2] = make_float2(v0, v1);
        }
        __syncthreads();

        // ---- own 6 gating values per column
        float gA[6], gB[6];
        #pragma unroll
        for (int p = 0; p < 3; ++p) {
            const float2 a = *(const float2*)&gv[cA * PAD + sub * 6 + p * 2];
            const float2 b = *(const float2*)&gv[cB * PAD + sub * 6 + p * 2];
            gA[p * 2] = a.x; gA[p * 2 + 1] = a.y;
            gB[p * 2] = b.x; gB[p * 2 + 1] = b.y;
        }

        // ---- strict-|.| rank: r[i] = #{j: |g_j| > |g_i|}  (full-rate f32 cmps)
        int rA[6] = {0, 0, 0, 0, 0, 0};
        int rB[6] = {0, 0, 0, 0, 0, 0};
        #pragma unroll
        for (int j4 = 0; j4 < 12; ++j4) {
            const float4 qa = *(const float4*)&gv[cA * PAD + j4 * 4];
            const float4 qb = *(const float4*)&gv[cB * PAD + j4 * 4];
            const float ja[4] = {qa.x, qa.y, qa.z, qa.w};
            const float jb[4] = {qb.x, qb.y, qb.z, qb.w};
            #pragma unroll
            for (int u = 0; u < 4; ++u) {
                #pragma unroll
                for (int ii = 0; ii < 6; ++ii) {
                    rA[ii] += (fabsf(ja[u]) > fabsf(gA[ii]));
                    rB[ii] += (fabsf(jb[u]) > fabsf(gB[ii]));
                }
            }
        }

        // ---- issue se loads early (consumed after tie check)
        float seA[6], seB[6];
        #pragma unroll
        for (int ii = 0; ii < 6; ++ii) {
            seA[ii] = se[(sub * 6 + ii) * M_TOT + colA];
            seB[ii] = se[(sub * 6 + ii) * M_TOT + colB];
        }

        // ---- tie detection: distinct-abs column has sum of strict ranks == 1128
        int SA = rA[0] + rA[1] + rA[2] + rA[3] + rA[4] + rA[5];
        int SB = rB[0] + rB[1] + rB[2] + rB[3] + rB[4] + rB[5];
        SA += __shfl_xor(SA, 1); SA += __shfl_xor(SA, 2); SA += __shfl_xor(SA, 4);
        SB += __shfl_xor(SB, 1); SB += __shfl_xor(SB, 2); SB += __shfl_xor(SB, 4);
        const bool tie = (SA != 1128) | (SB != 1128);

        if (__any(tie)) {
            // exact slow path (~0.03% of waves): u64 keys, stable tie-break
            uint64_t kA[6], kB[6];
            #pragma unroll
            for (int ii = 0; ii < 6; ++ii) {
                const uint32_t e = sub * 6 + ii;
                kA[ii] = ((uint64_t)(__float_as_uint(gA[ii]) & 0x7fffffffu) << 32)
                         | (uint32_t)(NEXP - 1 - e);
                kB[ii] = ((uint64_t)(__float_as_uint(gB[ii]) & 0x7fffffffu) << 32)
                         | (uint32_t)(NEXP - 1 - e);
                rA[ii] = 0; rB[ii] = 0;
            }
            #pragma unroll 1
            for (int j = 0; j < NEXP; ++j) {
                const uint64_t kja =
                    ((uint64_t)(__float_as_uint(gv[cA * PAD + j]) & 0x7fffffffu) << 32)
                    | (uint32_t)(NEXP - 1 - j);
                const uint64_t kjb =
                    ((uint64_t)(__float_as_uint(gv[cB * PAD + j]) & 0x7fffffffu) << 32)
                    | (uint32_t)(NEXP - 1 - j);
                #pragma unroll
                for (int ii = 0; ii < 6; ++ii) {
                    rA[ii] += (kja > kA[ii]);
                    rB[ii] += (kjb > kB[ii]);
                }
            }
        }

        // ---- masked contraction + 8-lane reduce + store
        float accA = 0.f, accB = 0.f;
        #pragma unroll
        for (int ii = 0; ii < 6; ++ii) {
            accA = (rA[ii] < K) ? fmaf(gA[ii], seA[ii], accA) : accA;
            accB = (rB[ii] < K) ? fmaf(gB[ii], seB[ii], accB) : accB;
        }
        accA += __shfl_xor(accA, 1); accA += __shfl_xor(accA, 2); accA += __shfl_xor(accA, 4);
        accB += __shfl_xor(accB, 1); accB += __shfl_xor(accB, 2); accB += __shfl_xor(accB, 4);
        if (sub == 0) {
            out[t * M_TOT + colA] = accA;
            out[t * M_TOT + colB] = accB;
        }
        __syncthreads();
    }
}

// Kernel 2: in-place softmax over the category dim (stride SP_TOT).
__global__ __launch_bounds__(256) void softmax_c(float* __restrict__ out)
{
    const int q = blockIdx.x * blockDim.x + threadIdx.x;
    if (q >= 2 * SP_TOT) return;
    const int t  = q / SP_TOT;
    const int sp = q - t * SP_TOT;
    float* __restrict__ base = out + t * M_TOT + sp;

    float v[NCAT];
    float mx = -INFINITY;
    #pragma unroll
    for (int c = 0; c < NCAT; ++c) {
        v[c] = base[c * SP_TOT];
        mx = fmaxf(mx, v[c]);
    }
    float sum = 0.f;
    #pragma unroll
    for (int c = 0; c < NCAT; ++c) {
        v[c] = __expf(v[c] - mx);
        sum += v[c];
    }
    const float inv = 1.f / sum;
    #pragma unroll
    for (int c = 0; c < NCAT; ++c)
        base[c * SP_TOT] = v[c] * inv;
}

extern "C" void kernel_launch(void* const* d_in, const int* in_sizes, int n_in,
                              void* d_out, int out_size, void* d_ws, size_t ws_size,
                              hipStream_t stream) {
    const float* gm   = (const float*)d_in[0];
    const float* gf   = (const float*)d_in[1];
    const float* se   = (const float*)d_in[2];
    const int*   kptr = (const int*)d_in[3];
    float* out = (float*)d_out;

    const int grid1 = M_TOT / CPB;                 // 6300
    moe_topk_contract<<<grid1, 256, 0, stream>>>(gm, gf, se, kptr, out);

    const int grid2 = (2 * SP_TOT + 255) / 256;    // 105
    softmax_c<<<grid2, 256, 0, stream>>>(out);
}